// Round 3
// baseline (89.009 us; speedup 1.0000x reference)
//
#include <hip/hip_runtime.h>

#define D 64
#define H 8
#define LSEQ 2048
#define KMAX 64
#define NCODES 256   // 2^H

// ---------------------------------------------------------------------------
// Kernel 1: LSH codes for BOTH query and key positions.
// code = sum_h ( (sum_{d: x[d]>0} W[d][h]) > 0 ) << h
// One thread per position, sequential over d (matches reference rounding —
// absmax was exactly 0 in R0/R1/R2 with this order; do not re-associate).
// Grid: 256 blocks x 64 threads -> one wave per CU.
// ---------------------------------------------------------------------------
__global__ void __launch_bounds__(64)
code_kernel(const float* __restrict__ query,
            const float* __restrict__ key,
            const float* __restrict__ W,
            int* __restrict__ q_code,   // [n_pos]
            int* __restrict__ k_code,   // [n_pos]
            int n_pos) {
    __shared__ float Ws[D * H];
    for (int i = threadIdx.x; i < D * H; i += blockDim.x) Ws[i] = W[i];
    __syncthreads();

    int t = blockIdx.x * blockDim.x + threadIdx.x;
    if (t >= 2 * n_pos) return;

    const float* xp = (t < n_pos) ? (query + (size_t)t * D)
                                  : (key + (size_t)(t - n_pos) * D);
    float s[H];
#pragma unroll
    for (int h = 0; h < H; ++h) s[h] = 0.0f;

    for (int d4 = 0; d4 < D / 4; ++d4) {
        float4 xv = ((const float4*)xp)[d4];
        const float* x4 = (const float*)&xv;
#pragma unroll
        for (int k = 0; k < 4; ++k) {
            if (x4[k] > 0.0f) {
                int d = d4 * 4 + k;
#pragma unroll
                for (int h = 0; h < H; ++h) s[h] += Ws[d * H + h];
            }
        }
    }
    int c = 0;
#pragma unroll
    for (int h = 0; h < H; ++h) c |= (s[h] > 0.0f) ? (1 << h) : 0;

    if (t < n_pos) q_code[t] = c;
    else           k_code[t - n_pos] = c;
}

// ---------------------------------------------------------------------------
// Kernel 2 (fused bucket + emit): one WAVE per (batch, code).
// Phase 1: ballot stream-compaction over k_code -> first <=KMAX ascending
//          matching key indices into an LDS row (init -1).
// Phase 2: sweep q_code; for every query with code c, all 64 lanes store the
//          row to out[(b,q,0:64)] -- one coalesced 256B store per match.
// bucket/cnt never touch global memory.
// ---------------------------------------------------------------------------
__global__ void __launch_bounds__(64)
bucket_emit_kernel(const int* __restrict__ q_code,   // [B][LSEQ]
                   const int* __restrict__ k_code,   // [B][LSEQ]
                   int* __restrict__ out) {          // [B][LSEQ][KMAX]
    __shared__ int row[KMAX];
    int c = blockIdx.x & (NCODES - 1);
    int b = blockIdx.x >> 8;
    int lane = threadIdx.x;   // block == one wave

    const int* kc = k_code + (size_t)b * LSEQ;
    const int* qc = q_code + (size_t)b * LSEQ;

    row[lane] = -1;
    __syncthreads();

    unsigned long long lt_mask = (lane == 63) ? 0x7FFFFFFFFFFFFFFFull
                                              : ((1ull << lane) - 1ull);
    // ---- Phase 1: build bucket row for code c ----
    int base = 0;
    for (int i = 0; i < LSEQ / 64; ++i) {
        int idx = i * 64 + lane;
        int ci = kc[idx];                             // coalesced, L2-hot
        unsigned long long mask = __ballot(ci == c);
        if (ci == c) {
            int rank = base + __popcll(mask & lt_mask);
            if (rank < KMAX) row[rank] = idx;
        }
        base += __popcll(mask);
        if (base >= KMAX) break;                      // wave-uniform
    }
    __syncthreads();
    int myval = row[lane];                            // -1 padded beyond count

    // ---- Phase 2: broadcast row to every query whose code == c ----
    for (int i = 0; i < LSEQ / 64; ++i) {
        int qi = i * 64 + lane;
        unsigned long long qmask = __ballot(qc[qi] == c);
        while (qmask) {
            int bit = (int)__ffsll((long long)qmask) - 1;   // wave-uniform
            int q = i * 64 + bit;
            out[((size_t)b * LSEQ + q) * KMAX + lane] = myval;  // 256B coalesced
            qmask &= qmask - 1;
        }
    }
}

extern "C" void kernel_launch(void* const* d_in, const int* in_sizes, int n_in,
                              void* d_out, int out_size, void* d_ws, size_t ws_size,
                              hipStream_t stream) {
    const float* query = (const float*)d_in[0];
    const float* key   = (const float*)d_in[1];
    const float* W     = (const float*)d_in[2];
    // d_in[3] = head_idx (unused)

    int n_pos = in_sizes[0] / D;        // B*L = 8192
    int B     = n_pos / LSEQ;           // 4

    int* q_code = (int*)d_ws;           // n_pos ints
    int* k_code = q_code + n_pos;       // n_pos ints

    {
        int total = 2 * n_pos;          // 16384 positions
        code_kernel<<<(total + 63) / 64, 64, 0, stream>>>(query, key, W,
                                                          q_code, k_code, n_pos);
    }
    {
        bucket_emit_kernel<<<B * NCODES, 64, 0, stream>>>(q_code, k_code,
                                                          (int*)d_out);
    }
}

// Round 4
// 80.465 us; speedup vs baseline: 1.1062x; 1.1062x over previous
//
#include <hip/hip_runtime.h>

#define D 64
#define H 8
#define LSEQ 2048
#define KMAX 64
#define NCODES 256   // 2^H

// ---------------------------------------------------------------------------
// Kernel 1: LSH codes for BOTH query and key positions.
// code = sum_h ( (sum_{d: x[d]>0} W[d][h]) > 0 ) << h
// Sequential over d (matches reference accumulation order — absmax has been
// exactly 0 every round with this order; do not re-associate).
// W rows read from LDS as two float4s (all lanes same addr -> broadcast).
// ---------------------------------------------------------------------------
__global__ void __launch_bounds__(256)
code_kernel(const float* __restrict__ query,
            const float* __restrict__ key,
            const float* __restrict__ W,
            int* __restrict__ q_code,   // [n_pos]
            int* __restrict__ k_code,   // [n_pos]
            int n_pos) {
    __shared__ float Ws[D * H];
    for (int i = threadIdx.x; i < D * H; i += blockDim.x) Ws[i] = W[i];
    __syncthreads();

    int t = blockIdx.x * blockDim.x + threadIdx.x;
    if (t >= 2 * n_pos) return;

    const float* xp = (t < n_pos) ? (query + (size_t)t * D)
                                  : (key + (size_t)(t - n_pos) * D);
    float4 s0 = {0.f, 0.f, 0.f, 0.f};
    float4 s1 = {0.f, 0.f, 0.f, 0.f};

    for (int d4 = 0; d4 < D / 4; ++d4) {
        float4 xv = ((const float4*)xp)[d4];
        const float* x4 = (const float*)&xv;
#pragma unroll
        for (int k = 0; k < 4; ++k) {
            if (x4[k] > 0.0f) {
                int d = d4 * 4 + k;
                float4 w0 = *(const float4*)&Ws[d * H + 0];   // LDS broadcast
                float4 w1 = *(const float4*)&Ws[d * H + 4];
                s0.x += w0.x; s0.y += w0.y; s0.z += w0.z; s0.w += w0.w;
                s1.x += w1.x; s1.y += w1.y; s1.z += w1.z; s1.w += w1.w;
            }
        }
    }
    int c = 0;
    c |= (s0.x > 0.0f) ? 1   : 0;
    c |= (s0.y > 0.0f) ? 2   : 0;
    c |= (s0.z > 0.0f) ? 4   : 0;
    c |= (s0.w > 0.0f) ? 8   : 0;
    c |= (s1.x > 0.0f) ? 16  : 0;
    c |= (s1.y > 0.0f) ? 32  : 0;
    c |= (s1.z > 0.0f) ? 64  : 0;
    c |= (s1.w > 0.0f) ? 128 : 0;

    if (t < n_pos) q_code[t] = c;
    else           k_code[t - n_pos] = c;
}

// ---------------------------------------------------------------------------
// Kernel 2: one WAVE per (batch, code). Ballot stream-compaction of the first
// <=KMAX ascending matching key indices into an LDS row (pre-padded -1),
// then ONE coalesced 256B store. No cnt array — padding encodes the count.
// ---------------------------------------------------------------------------
__global__ void __launch_bounds__(64)
bucket_ballot_kernel(const int* __restrict__ k_code,   // [B][LSEQ]
                     int* __restrict__ bucket) {       // [B][NCODES][KMAX]
    __shared__ int row[KMAX];
    int c = blockIdx.x & (NCODES - 1);
    int b = blockIdx.x >> 8;
    int lane = threadIdx.x;   // block == one wave

    const int* kc = k_code + (size_t)b * LSEQ;
    row[lane] = -1;

    unsigned long long lt_mask = (lane == 63) ? 0x7FFFFFFFFFFFFFFFull
                                              : ((1ull << lane) - 1ull);
    int base = 0;
    for (int i = 0; i < LSEQ / 64; ++i) {
        int idx = i * 64 + lane;
        int ci = kc[idx];                             // coalesced, L2-hot
        unsigned long long mask = __ballot(ci == c);
        if (ci == c) {
            int rank = base + __popcll(mask & lt_mask);
            if (rank < KMAX) row[rank] = idx;
        }
        base += __popcll(mask);
        if (base >= KMAX) break;                      // wave-uniform
    }
    __syncthreads();
    bucket[((size_t)b * NCODES + c) * KMAX + lane] = row[lane];  // 256B coalesced
}

// ---------------------------------------------------------------------------
// Kernel 3: emit. One thread per output element; each 64-lane wave serves one
// query: broadcast q_code read + coalesced 256B row copy. Branch-free.
// ---------------------------------------------------------------------------
__global__ void __launch_bounds__(256)
emit_kernel(const int* __restrict__ q_code,  // [B*LSEQ]
            const int* __restrict__ bucket,  // [B][NCODES][KMAX]
            int* __restrict__ out, int total) {
    int t = blockIdx.x * blockDim.x + threadIdx.x;
    if (t >= total) return;
    int q = t >> 6;                 // wave-uniform (KMAX = 64 = wave size)
    int j = t & (KMAX - 1);
    int b = q >> 11;                // LSEQ = 2048
    int c = q_code[q];              // broadcast load
    out[t] = bucket[((size_t)(b * NCODES + c)) * KMAX + j];
}

extern "C" void kernel_launch(void* const* d_in, const int* in_sizes, int n_in,
                              void* d_out, int out_size, void* d_ws, size_t ws_size,
                              hipStream_t stream) {
    const float* query = (const float*)d_in[0];
    const float* key   = (const float*)d_in[1];
    const float* W     = (const float*)d_in[2];
    // d_in[3] = head_idx (unused)

    int n_pos = in_sizes[0] / D;        // B*L = 8192
    int B     = n_pos / LSEQ;           // 4

    int* q_code = (int*)d_ws;           // n_pos ints
    int* k_code = q_code + n_pos;       // n_pos ints
    int* bucket = k_code + n_pos;       // B*NCODES*KMAX ints

    {
        int total = 2 * n_pos;          // 16384 positions
        code_kernel<<<(total + 255) / 256, 256, 0, stream>>>(query, key, W,
                                                             q_code, k_code, n_pos);
    }
    {
        bucket_ballot_kernel<<<B * NCODES, 64, 0, stream>>>(k_code, bucket);
    }
    {
        int total = out_size;           // B*L*KMAX
        emit_kernel<<<(total + 255) / 256, 256, 0, stream>>>(q_code, bucket,
                                                             (int*)d_out, total);
    }
}

// Round 5
// 78.516 us; speedup vs baseline: 1.1336x; 1.0248x over previous
//
#include <hip/hip_runtime.h>

#define D 64
#define H 8
#define LSEQ 2048
#define KMAX 64
#define NCODES 256   // 2^H

// ---------------------------------------------------------------------------
// Kernel 1: LSH codes for BOTH query and key positions.
// code = sum_h ( (sum_{d: x[d]>0} W[d][h]) > 0 ) << h
// Sequential over d (matches reference accumulation order — absmax has been
// exactly 0 every round with this order; do not re-associate).
// ---------------------------------------------------------------------------
__global__ void __launch_bounds__(256)
code_kernel(const float* __restrict__ query,
            const float* __restrict__ key,
            const float* __restrict__ W,
            int* __restrict__ q_code,   // [n_pos]
            int* __restrict__ k_code,   // [n_pos]
            int n_pos) {
    __shared__ float Ws[D * H];
    for (int i = threadIdx.x; i < D * H; i += blockDim.x) Ws[i] = W[i];
    __syncthreads();

    int t = blockIdx.x * blockDim.x + threadIdx.x;
    if (t >= 2 * n_pos) return;

    const float* xp = (t < n_pos) ? (query + (size_t)t * D)
                                  : (key + (size_t)(t - n_pos) * D);
    float4 s0 = {0.f, 0.f, 0.f, 0.f};
    float4 s1 = {0.f, 0.f, 0.f, 0.f};

    for (int d4 = 0; d4 < D / 4; ++d4) {
        float4 xv = ((const float4*)xp)[d4];
        const float* x4 = (const float*)&xv;
#pragma unroll
        for (int k = 0; k < 4; ++k) {
            if (x4[k] > 0.0f) {
                int d = d4 * 4 + k;
                float4 w0 = *(const float4*)&Ws[d * H + 0];   // LDS broadcast
                float4 w1 = *(const float4*)&Ws[d * H + 4];
                s0.x += w0.x; s0.y += w0.y; s0.z += w0.z; s0.w += w0.w;
                s1.x += w1.x; s1.y += w1.y; s1.z += w1.z; s1.w += w1.w;
            }
        }
    }
    int c = 0;
    c |= (s0.x > 0.0f) ? 1   : 0;
    c |= (s0.y > 0.0f) ? 2   : 0;
    c |= (s0.z > 0.0f) ? 4   : 0;
    c |= (s0.w > 0.0f) ? 8   : 0;
    c |= (s1.x > 0.0f) ? 16  : 0;
    c |= (s1.y > 0.0f) ? 32  : 0;
    c |= (s1.z > 0.0f) ? 64  : 0;
    c |= (s1.w > 0.0f) ? 128 : 0;

    if (t < n_pos) q_code[t] = c;
    else           k_code[t - n_pos] = c;
}

// ---------------------------------------------------------------------------
// Kernel 2 (fused scan + emit): one WAVE per QUERY (full parallelism — the
// R3 fused version was wave-serial over queries and regressed; this one
// keeps 8192 independent waves). Each wave:
//   - reads its query's code (broadcast),
//   - ballot stream-compacts the first <=KMAX ascending matching key indices
//     from the batch's 2048 key codes (32 coalesced, L2-hot chunks),
//   - builds the -1-padded row in its private LDS slice (no barrier: single
//     wave owns the slice; compiler inserts lgkmcnt waits),
//   - emits one coalesced 256B store.
// No bucket/cnt intermediates in global memory.
// ---------------------------------------------------------------------------
__global__ void __launch_bounds__(256)
scan_emit_kernel(const int* __restrict__ q_code,   // [B*LSEQ]
                 const int* __restrict__ k_code,   // [B][LSEQ]
                 int* __restrict__ out) {          // [B*LSEQ][KMAX]
    __shared__ int rows[4][KMAX];
    int wave = threadIdx.x >> 6;
    int lane = threadIdx.x & 63;
    int q = blockIdx.x * 4 + wave;       // global query index
    int b = q >> 11;                     // LSEQ = 2048

    int c = q_code[q];                   // wave-uniform broadcast load
    const int* kc = k_code + (size_t)b * LSEQ;
    int* row = rows[wave];
    row[lane] = -1;

    unsigned long long lt_mask = (lane == 63) ? 0x7FFFFFFFFFFFFFFFull
                                              : ((1ull << lane) - 1ull);
    int base = 0;
    for (int i = 0; i < LSEQ / 64; ++i) {
        int idx = i * 64 + lane;
        int ci = kc[idx];                             // coalesced, L2-hot
        unsigned long long mask = __ballot(ci == c);
        if (ci == c) {
            int rank = base + __popcll(mask & lt_mask);
            if (rank < KMAX) row[rank] = idx;
        }
        base += __popcll(mask);
        if (base >= KMAX) break;                      // wave-uniform
    }
    out[(size_t)q * KMAX + lane] = row[lane];         // 256B coalesced
}

extern "C" void kernel_launch(void* const* d_in, const int* in_sizes, int n_in,
                              void* d_out, int out_size, void* d_ws, size_t ws_size,
                              hipStream_t stream) {
    const float* query = (const float*)d_in[0];
    const float* key   = (const float*)d_in[1];
    const float* W     = (const float*)d_in[2];
    // d_in[3] = head_idx (unused)

    int n_pos = in_sizes[0] / D;        // B*L = 8192
    (void)ws_size;

    int* q_code = (int*)d_ws;           // n_pos ints
    int* k_code = q_code + n_pos;       // n_pos ints

    {
        int total = 2 * n_pos;          // 16384 positions
        code_kernel<<<(total + 255) / 256, 256, 0, stream>>>(query, key, W,
                                                             q_code, k_code, n_pos);
    }
    {
        // one wave per query, 4 waves per block
        scan_emit_kernel<<<n_pos / 4, 256, 0, stream>>>(q_code, k_code,
                                                        (int*)d_out);
    }
}

// Round 6
// 73.866 us; speedup vs baseline: 1.2050x; 1.0630x over previous
//
#include <hip/hip_runtime.h>

#define D 64
#define H 8
#define LSEQ 2048
#define KMAX 64
#define NCODES 256   // 2^H

// ---------------------------------------------------------------------------
// Kernel 1: LSH codes for BOTH query and key positions.
// code = sum_h ( (sum_{d: x[d]>0} W[d][h]) > 0 ) << h
// Sequential over d (matches reference accumulation order — absmax has been
// exactly 0 every round; do not re-associate).
// Query codes -> int array. Key codes -> PERMUTED byte array laid out so the
// scan kernel's uint load yields 4 ascending 64-chunks per lane:
//   byte for local pos (i*256 + j*64 + lane) lives at (i*256 + lane*4 + j).
// 64-thread blocks -> 256 blocks, one per CU.
// ---------------------------------------------------------------------------
__global__ void __launch_bounds__(64)
code_kernel(const float* __restrict__ query,
            const float* __restrict__ key,
            const float* __restrict__ W,
            int* __restrict__ q_code,            // [n_pos]
            unsigned char* __restrict__ kperm,   // [n_pos] permuted bytes
            int n_pos) {
    __shared__ float Ws[D * H];
    for (int i = threadIdx.x; i < D * H; i += blockDim.x) Ws[i] = W[i];
    __syncthreads();

    int t = blockIdx.x * blockDim.x + threadIdx.x;
    if (t >= 2 * n_pos) return;

    const float* xp = (t < n_pos) ? (query + (size_t)t * D)
                                  : (key + (size_t)(t - n_pos) * D);
    float4 s0 = {0.f, 0.f, 0.f, 0.f};
    float4 s1 = {0.f, 0.f, 0.f, 0.f};

    for (int d4 = 0; d4 < D / 4; ++d4) {
        float4 xv = ((const float4*)xp)[d4];
        const float* x4 = (const float*)&xv;
#pragma unroll
        for (int k = 0; k < 4; ++k) {
            if (x4[k] > 0.0f) {
                int d = d4 * 4 + k;
                float4 w0 = *(const float4*)&Ws[d * H + 0];   // LDS broadcast
                float4 w1 = *(const float4*)&Ws[d * H + 4];
                s0.x += w0.x; s0.y += w0.y; s0.z += w0.z; s0.w += w0.w;
                s1.x += w1.x; s1.y += w1.y; s1.z += w1.z; s1.w += w1.w;
            }
        }
    }
    int c = 0;
    c |= (s0.x > 0.0f) ? 1   : 0;
    c |= (s0.y > 0.0f) ? 2   : 0;
    c |= (s0.z > 0.0f) ? 4   : 0;
    c |= (s0.w > 0.0f) ? 8   : 0;
    c |= (s1.x > 0.0f) ? 16  : 0;
    c |= (s1.y > 0.0f) ? 32  : 0;
    c |= (s1.z > 0.0f) ? 64  : 0;
    c |= (s1.w > 0.0f) ? 128 : 0;

    if (t < n_pos) {
        q_code[t] = c;
    } else {
        int kk = t - n_pos;
        int b    = kk >> 11;            // LSEQ = 2048
        int l    = kk & (LSEQ - 1);
        int lane = l & 63;
        int j    = (l >> 6) & 3;
        int i4   = l >> 8;
        kperm[(b << 11) + (i4 << 8) + (lane << 2) + j] = (unsigned char)c;
    }
}

// ---------------------------------------------------------------------------
// Kernel 2 (fused scan + emit): one WAVE per QUERY. All 8 code-uints are
// PRELOADED into registers (no early exit -> loads fully pipelined), then
// 32 ballot sub-steps rank the first <=KMAX ascending matches into a
// -1-padded LDS row, emitted as one coalesced 256B store.
// ---------------------------------------------------------------------------
__global__ void __launch_bounds__(256)
scan_emit_kernel(const int* __restrict__ q_code,          // [B*LSEQ]
                 const unsigned int* __restrict__ kperm,  // [B][LSEQ/4]
                 int* __restrict__ out) {                 // [B*LSEQ][KMAX]
    __shared__ int rows[4][KMAX];
    int wave = threadIdx.x >> 6;
    int lane = threadIdx.x & 63;
    int q = blockIdx.x * 4 + wave;       // global query index
    int b = q >> 11;                     // LSEQ = 2048

    int c = q_code[q];                   // wave-uniform broadcast load
    const unsigned int* kp = kperm + (size_t)b * (LSEQ / 4) + lane;
    int* row = rows[wave];
    row[lane] = -1;

    unsigned int v[LSEQ / 256];          // 8 uints = 32 codes' worth per lane
#pragma unroll
    for (int i = 0; i < LSEQ / 256; ++i) v[i] = kp[i * 64];   // all in flight

    unsigned long long lt_mask = (lane == 63) ? 0x7FFFFFFFFFFFFFFFull
                                              : ((1ull << lane) - 1ull);
    int base = 0;
#pragma unroll
    for (int i = 0; i < LSEQ / 256; ++i) {
        unsigned int w = v[i];
#pragma unroll
        for (int j = 0; j < 4; ++j) {
            int ci = (int)((w >> (8 * j)) & 0xFFu);
            unsigned long long mask = __ballot(ci == c);
            if (ci == c) {
                int rank = base + __popcll(mask & lt_mask);
                if (rank < KMAX) row[rank] = i * 256 + j * 64 + lane;
            }
            base += __popcll(mask);
        }
    }
    out[(size_t)q * KMAX + lane] = row[lane];         // 256B coalesced
}

extern "C" void kernel_launch(void* const* d_in, const int* in_sizes, int n_in,
                              void* d_out, int out_size, void* d_ws, size_t ws_size,
                              hipStream_t stream) {
    const float* query = (const float*)d_in[0];
    const float* key   = (const float*)d_in[1];
    const float* W     = (const float*)d_in[2];
    // d_in[3] = head_idx (unused)

    int n_pos = in_sizes[0] / D;        // B*L = 8192
    (void)ws_size;

    int* q_code = (int*)d_ws;                         // n_pos ints (32 KB)
    unsigned char* kperm = (unsigned char*)(q_code + n_pos);  // n_pos bytes

    {
        int total = 2 * n_pos;          // 16384 positions, 64-thread blocks
        code_kernel<<<(total + 63) / 64, 64, 0, stream>>>(query, key, W,
                                                          q_code, kperm, n_pos);
    }
    {
        // one wave per query, 4 waves per block
        scan_emit_kernel<<<n_pos / 4, 256, 0, stream>>>(q_code,
                                                        (const unsigned int*)kperm,
                                                        (int*)d_out);
    }
}